// Round 2
// baseline (2294.784 us; speedup 1.0000x reference)
//
#include <hip/hip_runtime.h>
#include <cstdint>
#include <cstddef>

typedef __bf16 bf16x8 __attribute__((ext_vector_type(8)));
typedef float f32x4 __attribute__((ext_vector_type(4)));

#define HD 256
#define TLEN 1000
#define NSTEP 999

// ws layout (bf16 elements): W1R | W2R | W3R | W4R, fragment-ordered
#define W1R_OFF 0
#define W2R_OFF 16384
#define W3R_OFF 81920
#define W4R_OFF 147456
#define WS_ELEMS 151552

__device__ __forceinline__ void wg_barrier() {
  // LDS-only drain + barrier: do NOT force vmcnt(0) like __syncthreads does,
  // so the z-prefetch / out-stores stay in flight across layer barriers.
  asm volatile("s_waitcnt lgkmcnt(0)\n\ts_barrier" ::: "memory");
}

// Repack fp32 weights -> bf16 MFMA A-fragments in ws (runs every launch; ws is re-poisoned).
// Fragment element for (w,kb,tt,lane,j): k = kb*32 + (lane>>4)*8 + j ; n = w*32 + tt*16 + (lane&15)
// value = W[k][n] (b1 folded into W1 padded row k==48).
__global__ void prep_weights(const float* __restrict__ W1, const float* __restrict__ b1,
                             const float* __restrict__ W2, const float* __restrict__ W3,
                             const float* __restrict__ W4, __bf16* __restrict__ ws) {
  int tid = blockIdx.x * blockDim.x + threadIdx.x;
  if (tid >= WS_ELEMS) return;
  float val = 0.0f;
  if (tid < W2R_OFF) {                       // W1R: 8w x 2kb x 2tt x 64lane x 8j
    int t = tid;
    int j = t & 7, lane = (t >> 3) & 63, tt = (t >> 9) & 1, kb = (t >> 10) & 1, w = (t >> 11) & 7;
    int k = kb * 32 + ((lane >> 4) * 8) + j;
    int n = w * 32 + tt * 16 + (lane & 15);
    if (k < 48) val = W1[k * HD + n];
    else if (k == 48) val = b1[n];           // bias folded via constant-1 input at k=48
  } else if (tid < W3R_OFF) {                // W2R: 8w x 8kb x 2tt x 64 x 8
    int t = tid - W2R_OFF;
    int j = t & 7, lane = (t >> 3) & 63, tt = (t >> 9) & 1, kb = (t >> 10) & 7, w = (t >> 13) & 7;
    int k = kb * 32 + ((lane >> 4) * 8) + j;
    int n = w * 32 + tt * 16 + (lane & 15);
    val = W2[k * HD + n];
  } else if (tid < W4R_OFF) {                // W3R
    int t = tid - W3R_OFF;
    int j = t & 7, lane = (t >> 3) & 63, tt = (t >> 9) & 1, kb = (t >> 10) & 7, w = (t >> 13) & 7;
    int k = kb * 32 + ((lane >> 4) * 8) + j;
    int n = w * 32 + tt * 16 + (lane & 15);
    val = W3[k * HD + n];
  } else {                                   // W4R: 8kb x 64 x 8, N padded 8->16 with zeros
    int t = tid - W4R_OFF;
    int j = t & 7, lane = (t >> 3) & 63, kb = (t >> 9) & 7;
    int k = kb * 32 + ((lane >> 4) * 8) + j;
    int n = lane & 15;
    val = (n < 8) ? W4[k * 8 + n] : 0.0f;
  }
  ws[tid] = (__bf16)val;
}

// 4 waves x 64 hidden cols each; 1 wave/SIMD; weights resident in registers.
__global__ __launch_bounds__(256, 1) void ode_main(
    const float* __restrict__ t_g, const float* __restrict__ x_g,
    const float* __restrict__ z_g, const float* __restrict__ ev_g,
    const float* __restrict__ zj_g, const float* __restrict__ b2_g,
    const float* __restrict__ b3_g, const float* __restrict__ b4_g,
    const __bf16* __restrict__ ws, float* __restrict__ out) {
  __shared__ __align__(16) __bf16 h_a[16 * 264];   // 256 cols + 8 pad (row 528B)
  __shared__ __align__(16) __bf16 h_b[16 * 264];
  __shared__ __align__(16) float p4[4 * 16 * 8];   // layer-4 partials [wave][batch][dim]
  __shared__ __align__(16) float x_cur[16 * 12];
  __shared__ __align__(16) float z_eff[16 * 12];
  __shared__ __align__(16) float x0s[16 * 12];
  __shared__ __align__(16) float z0s[16 * 12];
  __shared__ __align__(16) float zjs[16 * 12];
  __shared__ float evs[16];

  const int tid  = threadIdx.x;
  const int lane = tid & 63;
  const int wid  = tid >> 6;     // 4 waves; wave w owns hidden cols [64w, 64w+64)
  const int bcol = lane & 15;    // batch column in MFMA B/C layout
  const int q    = lane >> 4;    // quad
  const int b0   = blockIdx.x * 16;

  // ---- stage per-batch constants ----
  if (tid < 128) {
    int m = tid >> 3, d = tid & 7;
    size_t gb = (size_t)(b0 + m);
    float x0 = x_g[gb * (TLEN * 8) + d];
    float z0 = z_g[gb * (TLEN * 8) + d];
    x0s[m * 12 + d] = x0;
    z0s[m * 12 + d] = z0;
    x_cur[m * 12 + d] = x0;
    zjs[m * 12 + d] = zj_g[gb * 8 + d];
    out[gb * (TLEN * 8) + d] = x0;           // sol[:,0] = x0
    if (d == 0) evs[m] = ev_g[gb];
  }
  __syncthreads();

  if (tid < 128) {  // z_eff for step 0
    int m = tid >> 3, d = tid & 7;
    float t0 = t_g[0];
    z_eff[m * 12 + d] = (t0 >= evs[m]) ? zjs[m * 12 + d] : z0s[m * 12 + d];
  }

  // ---- resident weight fragments (A-operand layout) ----
  // prep layout indexes col-groups of 32 (w8 = 0..7); wave wid owns w8 = {2*wid, 2*wid+1}.
  const bf16x8* wsv = (const bf16x8*)ws;
  bf16x8 w1f[2][4], w2f[8][4], w3f[8][4];
#pragma unroll
  for (int kb = 0; kb < 2; ++kb)
#pragma unroll
    for (int tt = 0; tt < 4; ++tt)
      w1f[kb][tt] = wsv[(W1R_OFF / 8) + (((2 * wid + (tt >> 1)) * 2 + kb) * 2 + (tt & 1)) * 64 + lane];
#pragma unroll
  for (int kb = 0; kb < 8; ++kb)
#pragma unroll
    for (int tt = 0; tt < 4; ++tt) {
      int idx = (((2 * wid + (tt >> 1)) * 8 + kb) * 2 + (tt & 1)) * 64 + lane;
      w2f[kb][tt] = wsv[(W2R_OFF / 8) + idx];
      w3f[kb][tt] = wsv[(W3R_OFF / 8) + idx];
    }
  bf16x8 w4f0 = wsv[(W4R_OFF / 8) + (2 * wid) * 64 + lane];
  bf16x8 w4f1 = wsv[(W4R_OFF / 8) + (2 * wid + 1) * 64 + lane];

  // biases as C-init: lane's 4 C rows are hidden n = wid*64 + tt*16 + q*4 + e
  f32x4 b2v[4], b3v[4];
#pragma unroll
  for (int tt = 0; tt < 4; ++tt) {
    int n0 = wid * 64 + tt * 16 + q * 4;
    b2v[tt] = *(const f32x4*)(b2_g + n0);
    b3v[tt] = *(const f32x4*)(b3_g + n0);
  }
  float b4l = (tid < 128) ? b4_g[tid & 7] : 0.0f;

  // wave-2 personals (z_eff producer): lane -> (m1, d0..d0+1)
  const int m1 = lane >> 2;
  const int d0 = (lane & 3) * 2;
  float2 zjf = make_float2(0.f, 0.f);
  float ev1 = 0.f;
  if (wid == 2) {
    zjf.x = zjs[m1 * 12 + d0];
    zjf.y = zjs[m1 * 12 + d0 + 1];
    ev1 = evs[m1];
  }

  // layer-1 per-lane B-frag constants:
  // kb=0: q0 k0-7 x0 | q1 k8-15 z0 | q2 k16-23 xc-x0 | q3 k24-31 ze-z0
  // kb=1: q0 k32-39 xc | q1 k40-47 ze | q2 k48 one (bias) | q3 zero
  f32x4 sub0, sub1;
  bf16x8 a0c;
  {
    const float* base = ((q & 1) ? z0s : x0s) + bcol * 12;
    f32x4 r0 = *(const f32x4*)(base);
    f32x4 r1 = *(const f32x4*)(base + 4);
    sub0 = r0; sub1 = r1;
#pragma unroll
    for (int e = 0; e < 4; ++e) { a0c[e] = (__bf16)r0[e]; a0c[e + 4] = (__bf16)r1[e]; }
  }
  bf16x8 zf;
#pragma unroll
  for (int e = 0; e < 8; ++e) zf[e] = (__bf16)0.f;
  bf16x8 k48f = zf;
  k48f[0] = (__bf16)1.0f;

  __syncthreads();

  float tc = t_g[0];

  auto layer_full = [&](const __bf16* src, __bf16* dst, const bf16x8 (*wf)[4], const f32x4* bv) {
    bf16x8 bfr[8];
    const bf16x8* hp = (const bf16x8*)src;
#pragma unroll
    for (int kb = 0; kb < 8; ++kb) bfr[kb] = hp[bcol * 33 + kb * 4 + q];  // ds_read_b128 x8
#pragma unroll
    for (int tt = 0; tt < 4; ++tt) {
      f32x4 c = bv[tt];
#pragma unroll
      for (int kb = 0; kb < 8; ++kb)
        c = __builtin_amdgcn_mfma_f32_16x16x32_bf16(wf[kb][tt], bfr[kb], c, 0, 0, 0);
      union { __bf16 h4[4]; unsigned long long u; } pk;
#pragma unroll
      for (int e = 0; e < 4; ++e) {
        float v = c[e];
        v = (v > 0.f) ? v : (__expf(v) - 1.0f);  // ELU
        pk.h4[e] = (__bf16)v;
      }
      *(unsigned long long*)(dst + bcol * 264 + wid * 64 + tt * 16 + q * 4) = pk.u;
    }
  };

#pragma unroll 1
  for (int i = 0; i < NSTEP; ++i) {
    float tn = t_g[i + 1];
    float2 zpre = make_float2(0.f, 0.f);
    if (wid == 2)  // prefetch z[:, i+1]; consumed in phase 4b of this step
      zpre = *(const float2*)(z_g + ((size_t)(b0 + m1) * TLEN + (i + 1)) * 8 + d0);

    // ---- phase 1: layer 1 (K padded 48->64, bias via k=48) ----
    {
      const float* rp = ((q & 1) ? z_eff : x_cur) + bcol * 12;
      f32x4 r0 = *(const f32x4*)(rp);
      f32x4 r1 = *(const f32x4*)(rp + 4);
      bf16x8 f0, f1;
      if (q < 2) {
        f0 = a0c;
#pragma unroll
        for (int e = 0; e < 4; ++e) { f1[e] = (__bf16)r0[e]; f1[e + 4] = (__bf16)r1[e]; }
      } else {
#pragma unroll
        for (int e = 0; e < 4; ++e) {
          f0[e] = (__bf16)(r0[e] - sub0[e]);
          f0[e + 4] = (__bf16)(r1[e] - sub1[e]);
        }
        f1 = (q == 2) ? k48f : zf;
      }
#pragma unroll
      for (int tt = 0; tt < 4; ++tt) {
        f32x4 c = {0.f, 0.f, 0.f, 0.f};
        c = __builtin_amdgcn_mfma_f32_16x16x32_bf16(w1f[0][tt], f0, c, 0, 0, 0);
        c = __builtin_amdgcn_mfma_f32_16x16x32_bf16(w1f[1][tt], f1, c, 0, 0, 0);
        union { __bf16 h4[4]; unsigned long long u; } pk;
#pragma unroll
        for (int e = 0; e < 4; ++e) {
          float v = c[e];
          v = (v > 0.f) ? v : (__expf(v) - 1.0f);
          pk.h4[e] = (__bf16)v;
        }
        *(unsigned long long*)(h_a + bcol * 264 + wid * 64 + tt * 16 + q * 4) = pk.u;
      }
    }
    wg_barrier();
    layer_full(h_a, h_b, w2f, b2v);   // phase 2: layer 2
    wg_barrier();
    layer_full(h_b, h_a, w3f, b3v);   // phase 3: layer 3 (h3 -> h_a)

    // ---- phase 3b (fused, no barrier): layer-4 partial on OWN columns ----
    // wave wid's layer-4 k-slice k in [64*wid, 64*wid+64) == the h3 cols it just wrote;
    // same-wave LDS write->read ordering is guaranteed by lgkmcnt waits.
    {
      const bf16x8* hp = (const bf16x8*)h_a;
      bf16x8 h40 = hp[bcol * 33 + (2 * wid) * 4 + q];
      bf16x8 h41 = hp[bcol * 33 + (2 * wid + 1) * 4 + q];
      f32x4 c = {0.f, 0.f, 0.f, 0.f};
      c = __builtin_amdgcn_mfma_f32_16x16x32_bf16(w4f0, h40, c, 0, 0, 0);
      c = __builtin_amdgcn_mfma_f32_16x16x32_bf16(w4f1, h41, c, 0, 0, 0);
      if (q < 2)  // valid out rows n = q*4+e < 8
        *(f32x4*)(p4 + wid * 128 + bcol * 8 + q * 4) = c;
    }
    wg_barrier();

    // ---- phase 4b: reduce + Euler (waves 0-1), z_eff(i+1) (wave 2) ----
    float dt = tn - tc;
    if (tid < 128) {
      int m = tid >> 3, d = tid & 7;
      float s = b4l;
#pragma unroll
      for (int j = 0; j < 4; ++j) s += p4[j * 128 + m * 8 + d];
      float xn = x_cur[m * 12 + d] + dt * s;
      x_cur[m * 12 + d] = xn;
      out[(size_t)(b0 + m) * (TLEN * 8) + (size_t)(i + 1) * 8 + d] = xn;
    } else if (wid == 2) {
      bool jmp = (tn >= ev1);
      float2 zev = make_float2(jmp ? zjf.x : zpre.x, jmp ? zjf.y : zpre.y);
      *(float2*)(z_eff + m1 * 12 + d0) = zev;
    }
    tc = tn;
    wg_barrier();
  }
}

extern "C" void kernel_launch(void* const* d_in, const int* in_sizes, int n_in,
                              void* d_out, int out_size, void* d_ws, size_t ws_size,
                              hipStream_t stream) {
  const float* t  = (const float*)d_in[0];
  const float* x  = (const float*)d_in[1];
  const float* z  = (const float*)d_in[2];
  const float* ev = (const float*)d_in[3];
  const float* zj = (const float*)d_in[4];
  const float* W1 = (const float*)d_in[5];
  const float* b1 = (const float*)d_in[6];
  const float* W2 = (const float*)d_in[7];
  const float* b2 = (const float*)d_in[8];
  const float* W3 = (const float*)d_in[9];
  const float* b3 = (const float*)d_in[10];
  const float* W4 = (const float*)d_in[11];
  const float* b4 = (const float*)d_in[12];
  __bf16* ws = (__bf16*)d_ws;
  float* out = (float*)d_out;

  prep_weights<<<592, 256, 0, stream>>>(W1, b1, W2, W3, W4, ws);
  ode_main<<<64, 256, 0, stream>>>(t, x, z, ev, zj, b2, b3, b4, ws, out);
}

// Round 3
// 1763.668 us; speedup vs baseline: 1.3011x; 1.3011x over previous
//
#include <hip/hip_runtime.h>
#include <cstdint>
#include <cstddef>

typedef __bf16 bf16x8 __attribute__((ext_vector_type(8)));
typedef float f32x4 __attribute__((ext_vector_type(4)));

#define HD 256
#define TLEN 1000
#define NSTEP 999

// ws layout (bf16 elements): W1R | W2R | W3R | W4R, fragment-ordered
#define W1R_OFF 0
#define W2R_OFF 16384
#define W3R_OFF 81920
#define W4R_OFF 147456
#define WS_ELEMS 151552

__device__ __forceinline__ void wg_barrier() {
  // LDS-only drain + barrier: do NOT force vmcnt(0) like __syncthreads does,
  // so the z-prefetch / out-stores stay in flight across layer barriers.
  asm volatile("s_waitcnt lgkmcnt(0)\n\ts_barrier" ::: "memory");
}

// Repack fp32 weights -> bf16 MFMA A-fragments in ws (runs every launch; ws is re-poisoned).
// Fragment element for (w,kb,tt,lane,j): k = kb*32 + (lane>>4)*8 + j ; n = w*32 + tt*16 + (lane&15)
// value = W[k][n] (b1 folded into W1 padded row k==48).
__global__ void prep_weights(const float* __restrict__ W1, const float* __restrict__ b1,
                             const float* __restrict__ W2, const float* __restrict__ W3,
                             const float* __restrict__ W4, __bf16* __restrict__ ws) {
  int tid = blockIdx.x * blockDim.x + threadIdx.x;
  if (tid >= WS_ELEMS) return;
  float val = 0.0f;
  if (tid < W2R_OFF) {                       // W1R: 8w x 2kb x 2tt x 64lane x 8j
    int t = tid;
    int j = t & 7, lane = (t >> 3) & 63, tt = (t >> 9) & 1, kb = (t >> 10) & 1, w = (t >> 11) & 7;
    int k = kb * 32 + ((lane >> 4) * 8) + j;
    int n = w * 32 + tt * 16 + (lane & 15);
    if (k < 48) val = W1[k * HD + n];
    else if (k == 48) val = b1[n];           // bias folded via constant-1 input at k=48
  } else if (tid < W3R_OFF) {                // W2R: 8w x 8kb x 2tt x 64 x 8
    int t = tid - W2R_OFF;
    int j = t & 7, lane = (t >> 3) & 63, tt = (t >> 9) & 1, kb = (t >> 10) & 7, w = (t >> 13) & 7;
    int k = kb * 32 + ((lane >> 4) * 8) + j;
    int n = w * 32 + tt * 16 + (lane & 15);
    val = W2[k * HD + n];
  } else if (tid < W4R_OFF) {                // W3R
    int t = tid - W3R_OFF;
    int j = t & 7, lane = (t >> 3) & 63, tt = (t >> 9) & 1, kb = (t >> 10) & 7, w = (t >> 13) & 7;
    int k = kb * 32 + ((lane >> 4) * 8) + j;
    int n = w * 32 + tt * 16 + (lane & 15);
    val = W3[k * HD + n];
  } else {                                   // W4R: 8kb x 64 x 8, N padded 8->16 with zeros
    int t = tid - W4R_OFF;
    int j = t & 7, lane = (t >> 3) & 63, kb = (t >> 9) & 7;
    int k = kb * 32 + ((lane >> 4) * 8) + j;
    int n = lane & 15;
    val = (n < 8) ? W4[k * 8 + n] : 0.0f;
  }
  ws[tid] = (__bf16)val;
}

// 8 waves x 32 hidden cols each; 2 waves/SIMD (latency hiding); weights in registers.
__global__ __launch_bounds__(512, 2) void ode_main(
    const float* __restrict__ t_g, const float* __restrict__ x_g,
    const float* __restrict__ z_g, const float* __restrict__ ev_g,
    const float* __restrict__ zj_g, const float* __restrict__ b2_g,
    const float* __restrict__ b3_g, const float* __restrict__ b4_g,
    const __bf16* __restrict__ ws, float* __restrict__ out) {
  __shared__ __align__(16) __bf16 h_a[16 * 264];   // 256 cols + 8 pad (row 528B)
  __shared__ __align__(16) __bf16 h_b[16 * 264];
  __shared__ __align__(16) float p4[8 * 16 * 8];   // layer-4 partials [wave][batch][dim]
  __shared__ __align__(16) float x_cur[16 * 12];
  __shared__ __align__(16) float z_eff[16 * 12];
  __shared__ __align__(16) float x0s[16 * 12];
  __shared__ __align__(16) float z0s[16 * 12];
  __shared__ __align__(16) float zjs[16 * 12];
  __shared__ float evs[16];

  const int tid  = threadIdx.x;
  const int lane = tid & 63;
  const int wid  = tid >> 6;     // 8 waves; wave w owns hidden cols [32w, 32w+32)
  const int bcol = lane & 15;    // batch column in MFMA B/C layout
  const int q    = lane >> 4;    // quad
  const int b0   = blockIdx.x * 16;

  // ---- stage per-batch constants ----
  if (tid < 128) {
    int m = tid >> 3, d = tid & 7;
    size_t gb = (size_t)(b0 + m);
    float x0 = x_g[gb * (TLEN * 8) + d];
    float z0 = z_g[gb * (TLEN * 8) + d];
    x0s[m * 12 + d] = x0;
    z0s[m * 12 + d] = z0;
    x_cur[m * 12 + d] = x0;
    zjs[m * 12 + d] = zj_g[gb * 8 + d];
    out[gb * (TLEN * 8) + d] = x0;           // sol[:,0] = x0
    if (d == 0) evs[m] = ev_g[gb];
  }
  __syncthreads();

  if (tid < 128) {  // z_eff for step 0
    int m = tid >> 3, d = tid & 7;
    float t0 = t_g[0];
    z_eff[m * 12 + d] = (t0 >= evs[m]) ? zjs[m * 12 + d] : z0s[m * 12 + d];
  }

  // ---- resident weight fragments (A-operand layout) ----
  const bf16x8* wsv = (const bf16x8*)ws;
  bf16x8 w1f[2][2], w2f[8][2], w3f[8][2];
#pragma unroll
  for (int kb = 0; kb < 2; ++kb)
#pragma unroll
    for (int tt = 0; tt < 2; ++tt)
      w1f[kb][tt] = wsv[(W1R_OFF / 8) + ((wid * 2 + kb) * 2 + tt) * 64 + lane];
#pragma unroll
  for (int kb = 0; kb < 8; ++kb)
#pragma unroll
    for (int tt = 0; tt < 2; ++tt) {
      w2f[kb][tt] = wsv[(W2R_OFF / 8) + ((wid * 8 + kb) * 2 + tt) * 64 + lane];
      w3f[kb][tt] = wsv[(W3R_OFF / 8) + ((wid * 8 + kb) * 2 + tt) * 64 + lane];
    }
  // W4 k-slice for this wave: k in [32*wid, 32*wid+32)
  bf16x8 w4f = wsv[(W4R_OFF / 8) + wid * 64 + lane];

  // biases as C-init: lane's 4 C rows are hidden n = wid*32 + tt*16 + q*4 + e
  f32x4 b2v[2], b3v[2];
#pragma unroll
  for (int tt = 0; tt < 2; ++tt) {
    int n0 = wid * 32 + tt * 16 + q * 4;
    b2v[tt] = *(const f32x4*)(b2_g + n0);
    b3v[tt] = *(const f32x4*)(b3_g + n0);
  }
  float b4l = (tid < 128) ? b4_g[tid & 7] : 0.0f;

  // wave-2 personals (z_eff producer; disjoint from the tid<128 reduce group)
  const int m1 = lane >> 2;
  const int d0 = (lane & 3) * 2;
  float2 zjf = make_float2(0.f, 0.f);
  float ev1 = 0.f;
  if (wid == 2) {
    zjf.x = zjs[m1 * 12 + d0];
    zjf.y = zjs[m1 * 12 + d0 + 1];
    ev1 = evs[m1];
  }

  // layer-1 per-lane B-frag constants:
  // q=0: k=0..7   -> x0 (const)          q=1: k=8..15  -> z0 (const)
  // q=2: k=16..23 -> x_cur - x0          q=3: k=24..31 -> z_eff - z0
  f32x4 sub0, sub1;
  bf16x8 a0c;
  {
    const float* base = ((q & 1) ? z0s : x0s) + bcol * 12;
    f32x4 r0 = *(const f32x4*)(base);
    f32x4 r1 = *(const f32x4*)(base + 4);
    sub0 = r0; sub1 = r1;
#pragma unroll
    for (int e = 0; e < 4; ++e) { a0c[e] = (__bf16)r0[e]; a0c[e + 4] = (__bf16)r1[e]; }
  }
  bf16x8 zf;
#pragma unroll
  for (int e = 0; e < 8; ++e) zf[e] = (__bf16)0.f;
  bf16x8 k48f = zf;
  k48f[0] = (__bf16)1.0f;  // constant-1 input at padded k=48 -> adds b1

  __syncthreads();

  float tc = t_g[0];

  auto layer = [&](const __bf16* src, __bf16* dst, const bf16x8 (*wf)[2], const f32x4* bv) {
    bf16x8 bfr[8];
    const bf16x8* hp = (const bf16x8*)src;
#pragma unroll
    for (int kb = 0; kb < 8; ++kb) bfr[kb] = hp[bcol * 33 + kb * 4 + q];  // ds_read_b128 x8
#pragma unroll
    for (int tt = 0; tt < 2; ++tt) {
      f32x4 c = bv[tt];
#pragma unroll
      for (int kb = 0; kb < 8; ++kb)
        c = __builtin_amdgcn_mfma_f32_16x16x32_bf16(wf[kb][tt], bfr[kb], c, 0, 0, 0);
      union { __bf16 h4[4]; unsigned long long u; } pk;
#pragma unroll
      for (int e = 0; e < 4; ++e) {
        float v = c[e];
        v = (v > 0.f) ? v : (__expf(v) - 1.0f);  // ELU
        pk.h4[e] = (__bf16)v;
      }
      // 4 consecutive hidden cols for batch bcol -> one ds_write_b64
      *(unsigned long long*)(dst + bcol * 264 + wid * 32 + tt * 16 + q * 4) = pk.u;
    }
  };

#pragma unroll 1
  for (int i = 0; i < NSTEP; ++i) {
    float tn = t_g[i + 1];
    float2 zpre = make_float2(0.f, 0.f);
    if (wid == 2)  // prefetch z[:, i+1]; consumed in phase 4 of this step
      zpre = *(const float2*)(z_g + ((size_t)(b0 + m1) * TLEN + (i + 1)) * 8 + d0);

    // ---- phase 1: layer 1 (K padded 48->64, bias via k=48) ----
    {
      const float* rp = ((q & 1) ? z_eff : x_cur) + bcol * 12;
      f32x4 r0 = *(const f32x4*)(rp);
      f32x4 r1 = *(const f32x4*)(rp + 4);
      bf16x8 f0, f1;
      if (q < 2) {
        f0 = a0c;
#pragma unroll
        for (int e = 0; e < 4; ++e) { f1[e] = (__bf16)r0[e]; f1[e + 4] = (__bf16)r1[e]; }
      } else {
#pragma unroll
        for (int e = 0; e < 4; ++e) {
          f0[e] = (__bf16)(r0[e] - sub0[e]);
          f0[e + 4] = (__bf16)(r1[e] - sub1[e]);
        }
        f1 = (q == 2) ? k48f : zf;
      }
#pragma unroll
      for (int tt = 0; tt < 2; ++tt) {
        f32x4 c = {0.f, 0.f, 0.f, 0.f};
        c = __builtin_amdgcn_mfma_f32_16x16x32_bf16(w1f[0][tt], f0, c, 0, 0, 0);
        c = __builtin_amdgcn_mfma_f32_16x16x32_bf16(w1f[1][tt], f1, c, 0, 0, 0);
        union { __bf16 h4[4]; unsigned long long u; } pk;
#pragma unroll
        for (int e = 0; e < 4; ++e) {
          float v = c[e];
          v = (v > 0.f) ? v : (__expf(v) - 1.0f);
          pk.h4[e] = (__bf16)v;
        }
        *(unsigned long long*)(h_a + bcol * 264 + wid * 32 + tt * 16 + q * 4) = pk.u;
      }
    }
    wg_barrier();
    layer(h_a, h_b, w2f, b2v);   // phase 2: layer 2
    wg_barrier();
    layer(h_b, h_a, w3f, b3v);   // phase 3: layer 3 (h3 -> h_a)

    // ---- phase 3b (fused, no barrier): layer-4 partial on OWN 32 columns ----
    // wave wid's layer-4 k-slice k in [32*wid, 32*wid+32) == the h3 cols it just
    // wrote; same-wave LDS write->read ordering guaranteed by lgkmcnt waits.
    {
      const bf16x8* hp = (const bf16x8*)h_a;
      bf16x8 h4 = hp[bcol * 33 + wid * 4 + q];
      f32x4 c = {0.f, 0.f, 0.f, 0.f};
      c = __builtin_amdgcn_mfma_f32_16x16x32_bf16(w4f, h4, c, 0, 0, 0);
      if (q < 2)  // valid out rows n = q*4+e < 8
        *(f32x4*)(p4 + wid * 128 + bcol * 8 + q * 4) = c;
    }
    wg_barrier();

    // ---- phase 4: reduce + Euler (waves 0-1), z_eff(i+1) (wave 2) ----
    float dt = tn - tc;
    if (tid < 128) {
      int m = tid >> 3, d = tid & 7;
      float s = b4l;
#pragma unroll
      for (int j = 0; j < 8; ++j) s += p4[j * 128 + m * 8 + d];
      float xn = x_cur[m * 12 + d] + dt * s;
      x_cur[m * 12 + d] = xn;
      out[(size_t)(b0 + m) * (TLEN * 8) + (size_t)(i + 1) * 8 + d] = xn;
    } else if (wid == 2) {
      bool jmp = (tn >= ev1);
      float2 zev = make_float2(jmp ? zjf.x : zpre.x, jmp ? zjf.y : zpre.y);
      *(float2*)(z_eff + m1 * 12 + d0) = zev;
    }
    tc = tn;
    wg_barrier();
  }
}

extern "C" void kernel_launch(void* const* d_in, const int* in_sizes, int n_in,
                              void* d_out, int out_size, void* d_ws, size_t ws_size,
                              hipStream_t stream) {
  const float* t  = (const float*)d_in[0];
  const float* x  = (const float*)d_in[1];
  const float* z  = (const float*)d_in[2];
  const float* ev = (const float*)d_in[3];
  const float* zj = (const float*)d_in[4];
  const float* W1 = (const float*)d_in[5];
  const float* b1 = (const float*)d_in[6];
  const float* W2 = (const float*)d_in[7];
  const float* b2 = (const float*)d_in[8];
  const float* W3 = (const float*)d_in[9];
  const float* b3 = (const float*)d_in[10];
  const float* W4 = (const float*)d_in[11];
  const float* b4 = (const float*)d_in[12];
  __bf16* ws = (__bf16*)d_ws;
  float* out = (float*)d_out;

  prep_weights<<<592, 256, 0, stream>>>(W1, b1, W2, W3, W4, ws);
  ode_main<<<64, 512, 0, stream>>>(t, x, z, ev, zj, b2, b3, b4, ws, out);
}

// Round 4
// 1760.227 us; speedup vs baseline: 1.3037x; 1.0020x over previous
//
#include <hip/hip_runtime.h>
#include <cstdint>
#include <cstddef>

typedef __bf16 bf16x8 __attribute__((ext_vector_type(8)));
typedef float f32x4 __attribute__((ext_vector_type(4)));

#define HD 256
#define TLEN 1000
#define NSTEP 999

// ws layout (bf16 elements): W1R | W2R | W3R | W4R, fragment-ordered
#define W1R_OFF 0
#define W2R_OFF 16384
#define W3R_OFF 81920
#define W4R_OFF 147456
#define WS_ELEMS 151552

__device__ __forceinline__ void wg_barrier() {
  // LDS-only drain + barrier: do NOT force vmcnt(0) like __syncthreads does,
  // so the z-prefetch / out-stores stay in flight across layer barriers.
  asm volatile("s_waitcnt lgkmcnt(0)\n\ts_barrier" ::: "memory");
}

// Repack fp32 weights -> bf16 MFMA A-fragments in ws (runs every launch; ws is re-poisoned).
// Fragment element for (w,kb,tt,lane,j): k = kb*32 + (lane>>4)*8 + j ; n = w*32 + tt*16 + (lane&15)
// value = W[k][n] (b1 folded into W1 padded row k==48).
__global__ void prep_weights(const float* __restrict__ W1, const float* __restrict__ b1,
                             const float* __restrict__ W2, const float* __restrict__ W3,
                             const float* __restrict__ W4, __bf16* __restrict__ ws) {
  int tid = blockIdx.x * blockDim.x + threadIdx.x;
  if (tid >= WS_ELEMS) return;
  float val = 0.0f;
  if (tid < W2R_OFF) {                       // W1R: 8w x 2kb x 2tt x 64lane x 8j
    int t = tid;
    int j = t & 7, lane = (t >> 3) & 63, tt = (t >> 9) & 1, kb = (t >> 10) & 1, w = (t >> 11) & 7;
    int k = kb * 32 + ((lane >> 4) * 8) + j;
    int n = w * 32 + tt * 16 + (lane & 15);
    if (k < 48) val = W1[k * HD + n];
    else if (k == 48) val = b1[n];           // bias folded via constant-1 input at k=48
  } else if (tid < W3R_OFF) {                // W2R: 8w x 8kb x 2tt x 64 x 8
    int t = tid - W2R_OFF;
    int j = t & 7, lane = (t >> 3) & 63, tt = (t >> 9) & 1, kb = (t >> 10) & 7, w = (t >> 13) & 7;
    int k = kb * 32 + ((lane >> 4) * 8) + j;
    int n = w * 32 + tt * 16 + (lane & 15);
    val = W2[k * HD + n];
  } else if (tid < W4R_OFF) {                // W3R
    int t = tid - W3R_OFF;
    int j = t & 7, lane = (t >> 3) & 63, tt = (t >> 9) & 1, kb = (t >> 10) & 7, w = (t >> 13) & 7;
    int k = kb * 32 + ((lane >> 4) * 8) + j;
    int n = w * 32 + tt * 16 + (lane & 15);
    val = W3[k * HD + n];
  } else {                                   // W4R: 8kb x 64 x 8, N padded 8->16 with zeros
    int t = tid - W4R_OFF;
    int j = t & 7, lane = (t >> 3) & 63, kb = (t >> 9) & 7;
    int k = kb * 32 + ((lane >> 4) * 8) + j;
    int n = lane & 15;
    val = (n < 8) ? W4[k * 8 + n] : 0.0f;
  }
  ws[tid] = (__bf16)val;
}

// Batch tile 8 -> 128 WGs -> 128 CUs (2x CUs vs round 3); 8 waves x 32 cols,
// 2 waves/SIMD TLP preserved. B-operand cols 8-15 are dead (zero-fed) — wasted
// MFMA lanes bought 2x more CUs and half the per-CU LDS traffic.
__global__ __launch_bounds__(512, 2) void ode_main(
    const float* __restrict__ t_g, const float* __restrict__ x_g,
    const float* __restrict__ z_g, const float* __restrict__ ev_g,
    const float* __restrict__ zj_g, const float* __restrict__ b2_g,
    const float* __restrict__ b3_g, const float* __restrict__ b4_g,
    const __bf16* __restrict__ ws, float* __restrict__ out) {
  __shared__ __align__(16) __bf16 h_a[16 * 264];   // 16 rows kept (8 live + 8 dead), row 528B
  __shared__ __align__(16) __bf16 h_b[16 * 264];
  __shared__ __align__(16) float p4[8 * 16 * 8];   // layer-4 partials [wave][bcol][dim]
  __shared__ __align__(16) float x_cur[16 * 12];
  __shared__ __align__(16) float z_eff[16 * 12];
  __shared__ __align__(16) float x0s[16 * 12];
  __shared__ __align__(16) float z0s[16 * 12];
  __shared__ __align__(16) float zjs[16 * 12];
  __shared__ float evs[16];

  const int tid  = threadIdx.x;
  const int lane = tid & 63;
  const int wid  = tid >> 6;     // 8 waves; wave w owns hidden cols [32w, 32w+32)
  const int bcol = lane & 15;    // B/C-operand column; batch row if < 8, dead otherwise
  const int q    = lane >> 4;    // quad
  const int b0   = blockIdx.x * 8;

  // ---- stage per-batch constants (rows 8-15 zeroed: dead cols stay finite) ----
  if (tid < 128) {
    int m = tid >> 3, d = tid & 7;
    if (m < 8) {
      size_t gb = (size_t)(b0 + m);
      float x0 = x_g[gb * (TLEN * 8) + d];
      float z0 = z_g[gb * (TLEN * 8) + d];
      x0s[m * 12 + d] = x0;
      z0s[m * 12 + d] = z0;
      x_cur[m * 12 + d] = x0;
      zjs[m * 12 + d] = zj_g[gb * 8 + d];
      out[gb * (TLEN * 8) + d] = x0;         // sol[:,0] = x0
      if (d == 0) evs[m] = ev_g[gb];
    } else {
      x0s[m * 12 + d] = 0.f;
      z0s[m * 12 + d] = 0.f;
      x_cur[m * 12 + d] = 0.f;
      zjs[m * 12 + d] = 0.f;
      if (d == 0) evs[m] = 0.f;
    }
  }
  __syncthreads();

  if (tid < 128) {  // z_eff for step 0 (rows >=8 resolve to 0)
    int m = tid >> 3, d = tid & 7;
    float t0 = t_g[0];
    z_eff[m * 12 + d] = (t0 >= evs[m]) ? zjs[m * 12 + d] : z0s[m * 12 + d];
  }

  // ---- resident weight fragments (A-operand layout) ----
  const bf16x8* wsv = (const bf16x8*)ws;
  bf16x8 w1f[2][2], w2f[8][2], w3f[8][2];
#pragma unroll
  for (int kb = 0; kb < 2; ++kb)
#pragma unroll
    for (int tt = 0; tt < 2; ++tt)
      w1f[kb][tt] = wsv[(W1R_OFF / 8) + ((wid * 2 + kb) * 2 + tt) * 64 + lane];
#pragma unroll
  for (int kb = 0; kb < 8; ++kb)
#pragma unroll
    for (int tt = 0; tt < 2; ++tt) {
      w2f[kb][tt] = wsv[(W2R_OFF / 8) + ((wid * 8 + kb) * 2 + tt) * 64 + lane];
      w3f[kb][tt] = wsv[(W3R_OFF / 8) + ((wid * 8 + kb) * 2 + tt) * 64 + lane];
    }
  // W4 k-slice for this wave: k in [32*wid, 32*wid+32)
  bf16x8 w4f = wsv[(W4R_OFF / 8) + wid * 64 + lane];

  // biases as C-init: lane's 4 C rows are hidden n = wid*32 + tt*16 + q*4 + e
  f32x4 b2v[2], b3v[2];
#pragma unroll
  for (int tt = 0; tt < 2; ++tt) {
    int n0 = wid * 32 + tt * 16 + q * 4;
    b2v[tt] = *(const f32x4*)(b2_g + n0);
    b3v[tt] = *(const f32x4*)(b3_g + n0);
  }
  float b4l = (tid < 64) ? b4_g[tid & 7] : 0.0f;

  // wave-2 personals (z_eff producer): lanes 0-31 cover (m 0-7) x (d pairs)
  const int m1 = lane >> 2;          // 0..15, only <8 used
  const int d0 = (lane & 3) * 2;
  float2 zjf = make_float2(0.f, 0.f);
  float ev1 = 0.f;
  const bool zprod = (wid == 2) && (lane < 32);
  if (zprod) {
    zjf.x = zjs[m1 * 12 + d0];
    zjf.y = zjs[m1 * 12 + d0 + 1];
    ev1 = evs[m1];
  }

  // layer-1 per-lane B-frag constants:
  // q=0: k=0..7   -> x0 (const)          q=1: k=8..15  -> z0 (const)
  // q=2: k=16..23 -> x_cur - x0          q=3: k=24..31 -> z_eff - z0
  f32x4 sub0, sub1;
  bf16x8 a0c;
  {
    const float* base = ((q & 1) ? z0s : x0s) + bcol * 12;
    f32x4 r0 = *(const f32x4*)(base);
    f32x4 r1 = *(const f32x4*)(base + 4);
    sub0 = r0; sub1 = r1;
#pragma unroll
    for (int e = 0; e < 4; ++e) { a0c[e] = (__bf16)r0[e]; a0c[e + 4] = (__bf16)r1[e]; }
  }
  bf16x8 zf;
#pragma unroll
  for (int e = 0; e < 8; ++e) zf[e] = (__bf16)0.f;
  bf16x8 k48f = zf;
  k48f[0] = (__bf16)1.0f;  // constant-1 input at padded k=48 -> adds b1

  __syncthreads();

  float tc = t_g[0];

  auto layer = [&](const __bf16* src, __bf16* dst, const bf16x8 (*wf)[2], const f32x4* bv) {
    bf16x8 bfr[8];
    const bf16x8* hp = (const bf16x8*)src;
#pragma unroll
    for (int kb = 0; kb < 8; ++kb) bfr[kb] = hp[bcol * 33 + kb * 4 + q];  // ds_read_b128 x8
#pragma unroll
    for (int tt = 0; tt < 2; ++tt) {
      f32x4 c = bv[tt];
#pragma unroll
      for (int kb = 0; kb < 8; ++kb)
        c = __builtin_amdgcn_mfma_f32_16x16x32_bf16(wf[kb][tt], bfr[kb], c, 0, 0, 0);
      union { __bf16 h4[4]; unsigned long long u; } pk;
#pragma unroll
      for (int e = 0; e < 4; ++e) {
        float v = c[e];
        v = (v > 0.f) ? v : (__expf(v) - 1.0f);  // ELU
        pk.h4[e] = (__bf16)v;
      }
      // 4 consecutive hidden cols for batch bcol -> one ds_write_b64
      *(unsigned long long*)(dst + bcol * 264 + wid * 32 + tt * 16 + q * 4) = pk.u;
    }
  };

#pragma unroll 1
  for (int i = 0; i < NSTEP; ++i) {
    float tn = t_g[i + 1];
    float2 zpre = make_float2(0.f, 0.f);
    if (zprod)  // prefetch z[:, i+1]; consumed in phase 4 of this step
      zpre = *(const float2*)(z_g + ((size_t)(b0 + m1) * TLEN + (i + 1)) * 8 + d0);

    // ---- phase 1: layer 1 (K padded 48->64, bias via k=48) ----
    {
      const float* rp = ((q & 1) ? z_eff : x_cur) + bcol * 12;
      f32x4 r0 = *(const f32x4*)(rp);
      f32x4 r1 = *(const f32x4*)(rp + 4);
      bf16x8 f0, f1;
      if (q < 2) {
        f0 = a0c;
#pragma unroll
        for (int e = 0; e < 4; ++e) { f1[e] = (__bf16)r0[e]; f1[e + 4] = (__bf16)r1[e]; }
      } else {
#pragma unroll
        for (int e = 0; e < 4; ++e) {
          f0[e] = (__bf16)(r0[e] - sub0[e]);
          f0[e + 4] = (__bf16)(r1[e] - sub1[e]);
        }
        f1 = (q == 2) ? k48f : zf;
      }
#pragma unroll
      for (int tt = 0; tt < 2; ++tt) {
        f32x4 c = {0.f, 0.f, 0.f, 0.f};
        c = __builtin_amdgcn_mfma_f32_16x16x32_bf16(w1f[0][tt], f0, c, 0, 0, 0);
        c = __builtin_amdgcn_mfma_f32_16x16x32_bf16(w1f[1][tt], f1, c, 0, 0, 0);
        union { __bf16 h4[4]; unsigned long long u; } pk;
#pragma unroll
        for (int e = 0; e < 4; ++e) {
          float v = c[e];
          v = (v > 0.f) ? v : (__expf(v) - 1.0f);
          pk.h4[e] = (__bf16)v;
        }
        *(unsigned long long*)(h_a + bcol * 264 + wid * 32 + tt * 16 + q * 4) = pk.u;
      }
    }
    wg_barrier();
    layer(h_a, h_b, w2f, b2v);   // phase 2: layer 2
    wg_barrier();
    layer(h_b, h_a, w3f, b3v);   // phase 3: layer 3 (h3 -> h_a)

    // ---- phase 3b (fused, no barrier): layer-4 partial on OWN 32 columns ----
    {
      const bf16x8* hp = (const bf16x8*)h_a;
      bf16x8 h4 = hp[bcol * 33 + wid * 4 + q];
      f32x4 c = {0.f, 0.f, 0.f, 0.f};
      c = __builtin_amdgcn_mfma_f32_16x16x32_bf16(w4f, h4, c, 0, 0, 0);
      if (q < 2)  // valid out rows n = q*4+e < 8
        *(f32x4*)(p4 + wid * 128 + bcol * 8 + q * 4) = c;
    }
    wg_barrier();

    // ---- phase 4: reduce + Euler (wave 0, 64 thr), z_eff(i+1) (wave 2) ----
    float dt = tn - tc;
    if (tid < 64) {
      int m = tid >> 3, d = tid & 7;   // m in 0..7: live batch rows only
      float s = b4l;
#pragma unroll
      for (int j = 0; j < 8; ++j) s += p4[j * 128 + m * 8 + d];
      float xn = x_cur[m * 12 + d] + dt * s;
      x_cur[m * 12 + d] = xn;
      out[(size_t)(b0 + m) * (TLEN * 8) + (size_t)(i + 1) * 8 + d] = xn;
    } else if (zprod) {
      bool jmp = (tn >= ev1);
      float2 zev = make_float2(jmp ? zjf.x : zpre.x, jmp ? zjf.y : zpre.y);
      *(float2*)(z_eff + m1 * 12 + d0) = zev;
    }
    tc = tn;
    wg_barrier();
  }
}

extern "C" void kernel_launch(void* const* d_in, const int* in_sizes, int n_in,
                              void* d_out, int out_size, void* d_ws, size_t ws_size,
                              hipStream_t stream) {
  const float* t  = (const float*)d_in[0];
  const float* x  = (const float*)d_in[1];
  const float* z  = (const float*)d_in[2];
  const float* ev = (const float*)d_in[3];
  const float* zj = (const float*)d_in[4];
  const float* W1 = (const float*)d_in[5];
  const float* b1 = (const float*)d_in[6];
  const float* W2 = (const float*)d_in[7];
  const float* b2 = (const float*)d_in[8];
  const float* W3 = (const float*)d_in[9];
  const float* b3 = (const float*)d_in[10];
  const float* W4 = (const float*)d_in[11];
  const float* b4 = (const float*)d_in[12];
  __bf16* ws = (__bf16*)d_ws;
  float* out = (float*)d_out;

  prep_weights<<<592, 256, 0, stream>>>(W1, b1, W2, W3, W4, ws);
  ode_main<<<128, 512, 0, stream>>>(t, x, z, ev, zj, b2, b3, b4, ws, out);
}